// Round 11
// baseline (956.956 us; speedup 1.0000x reference)
//
#include <hip/hip_runtime.h>

// NeuroVoltron v15: v14 + residual bank-conflict pads + full-cover fetch.
//  - Pads: giSS/ghSS stride 96->100, hSS 32->36, shSS 64->68, gateS 32->36
//    (kills the remaining 4-way cross-g aliasing behind v14's 7.5M conflicts).
//  - P4 fetch cover: EVERY fetch lane computes before its first poll (msgs on
//    0-175, GRU on 176-303, s_sleep(4) on 304-351) so no lane burns a miss RT;
//    phase ends at max over lanes, so full cover is what matters.
//  - gh moved P2->P1 (needs only prev-step hSS); P2 = inc only + W7 drain.
//  - Spinners W0-5 never publish; publishers W6-7 never spin (invariant).
//  - Exchange identical to v9-v14: NaN-sentinel data-poll, 3 rotating buffers,
//    lgkm-only barriers, 72KB dynamic LDS => 1 block/CU.
// All dot-product summation orders unchanged => absmax 0.015625.

constexpr int R  = 12;
constexpr int L  = 32;
constexpr int M  = 16;
constexpr int HH = 32;
constexpr int HF = 64;
constexpr int E  = 132;
constexpr int G3 = 96;      // 3*HH
constexpr float DT = 0.1f;

constexpr int G  = 4;       // batch elements per block
constexpr int BS = 512;
constexpr int ZR = 36;      // zS room stride (floats)
constexpr int ZG = R * ZR;  // 432
constexpr int IS = 36;      // incS g stride
constexpr int HS = 36;      // hSS g stride
constexpr int SH = 68;      // shSS g stride
constexpr int GS = 36;      // gateS g stride
constexpr int GG = 100;     // giSS/ghSS g stride

typedef float f4v __attribute__((ext_vector_type(4)));   // nt-store-compatible

__device__ __forceinline__ float sigmoidf(float x) {
    return 1.0f / (1.0f + __expf(-x));
}
__device__ __forceinline__ float fma4(float4 a, float4 x, float acc) {
    acc = fmaf(a.x, x.x, acc);
    acc = fmaf(a.y, x.y, acc);
    acc = fmaf(a.z, x.z, acc);
    return fmaf(a.w, x.w, acc);
}

// Raw block barrier: LDS-only ordering (lgkmcnt), no vmcnt drain.
__device__ __forceinline__ void sync_lds() {
    asm volatile("s_waitcnt lgkmcnt(0)" ::: "memory");
    __builtin_amdgcn_s_barrier();
    asm volatile("" ::: "memory");
}

__global__ __launch_bounds__(BS)
__attribute__((amdgpu_waves_per_eu(2, 2)))
void nv_main(
    const float* __restrict__ z0,     const float* __restrict__ h0,
    const float* __restrict__ mean_w, const float* __restrict__ mean_b,
    const float* __restrict__ add_w,
    const float* __restrict__ gsw,    const float* __restrict__ gsb,
    const float* __restrict__ gcw,
    const float* __restrict__ lw,     const float* __restrict__ lb,
    const float* __restrict__ ow_w,   const float* __restrict__ ob,
    const float* __restrict__ wih,    const float* __restrict__ whh,
    const float* __restrict__ bih,    const float* __restrict__ bhh,
    const int* __restrict__ src_idx,  const int* __restrict__ tgt_idx,
    const int* __restrict__ n_steps_p,
    float* __restrict__ zx,
    float* __restrict__ out, int B)
{
    const int r   = blockIdx.x;       // room
    const int grp = blockIdx.y;       // batch group
    const int tid = threadIdx.x;
    const int T   = n_steps_p[0];
    const int b0  = grp * G;
    const size_t ZXN = (size_t)B * (R * L);   // one buffer's floats

    // output layout: z_traj (B,T,R,L) | h_f (B,R,HH) | msgs (B,T,E,M)
    float* __restrict__ out_z    = out;
    float* __restrict__ out_hf   = out + (size_t)B * T * R * L;
    float* __restrict__ out_msgs = out_hf + (size_t)B * R * HH;

    __shared__ __align__(16) float wadd_s[11 * L * M];   // [(e*4+c)*32+l] f4 over m
    __shared__ __align__(16) float wih_s[G3 * L];        // XOR-swizzled chunks
    __shared__ __align__(16) float zS[G * ZG];           // [g][room(ZR)][l]
    __shared__ __align__(16) float hSS[G * HS];
    __shared__ __align__(16) float meanS[G * 11 * M];    // [g][row]
    __shared__ __align__(16) float incS[G * IS];
    __shared__ __align__(16) float gateS[G * GS];
    __shared__ __align__(16) float shSS[G * SH];
    __shared__ __align__(16) float giSS[G * GG];
    __shared__ __align__(16) float ghSS[G * GG];
    __shared__ int edgeE[11], edgeSrc[11];

    // ---- edge tables for this room ----
    if (tid == 0) {
        int c = 0;
        for (int e = 0; e < E; ++e)
            if (tgt_idx[e] == r) { edgeE[c] = e; edgeSrc[c] = src_idx[e]; ++c; }
    }
    __syncthreads();

    // ---- one-time: weights into role-slotted wbuf[32] (max 24 f4 used) ----
    // [0..7]:  meanW (0-351, row tid%176) | ghW (384-479)
    // [8..23]: siluW (0-255) | gateW gsw+gcw (256-383) | owW (384-511)
    float4 wbuf[32];
    float biasA = 0.f, biasB = 0.f, biasC = 0.f;

    if (tid < 352) {                       // meanW -> [0..7]
        const int rowl = tid % 176;
        const int el = rowl >> 4, m = rowl & 15;
        const int row = edgeE[el] * M + m;
        const float4* p = (const float4*)(mean_w + (size_t)row * L);
#pragma unroll
        for (int k = 0; k < 8; ++k) wbuf[k] = p[k];
        biasA = mean_b[row];
    }
    if (tid >= 384 && tid < 480) {         // ghW -> [0..7]
        const int j = tid - 384, row = r * G3 + j;
        const float4* p = (const float4*)(whh + (size_t)row * HH);
#pragma unroll
        for (int k = 0; k < 8; ++k) wbuf[k] = p[k];
        biasA = bhh[row];
    }
    if (tid < 256) {                       // siluW -> [8..23]
        const int j = tid & 63, row = r * HF + j;
        const float4* p = (const float4*)(lw + (size_t)row * 2 * L);
#pragma unroll
        for (int k = 0; k < 16; ++k) wbuf[8 + k] = p[k];
        biasB = lb[row];
    }
    if (tid >= 256 && tid < 384) {         // gateW: gsw->[8..15], gcw->[16..23]
        const int j = (tid - 256) & 31, row = r * L + j;
        const float4* pa = (const float4*)(gsw + (size_t)row * L);
        const float4* pb = (const float4*)(gcw + (size_t)row * L);
#pragma unroll
        for (int k = 0; k < 8; ++k) { wbuf[8 + k] = pa[k]; wbuf[16 + k] = pb[k]; }
        biasB = gsb[row];
    }
    if (tid >= 384) {                      // owW -> [8..23]
        const int j = (tid - 384) & 31, row = r * L + j;
        const float4* p = (const float4*)(ow_w + (size_t)row * HF);
#pragma unroll
        for (int k = 0; k < 16; ++k) wbuf[8 + k] = p[k];
        biasB = ob[row];
    }
    if (tid >= 128) {                      // gi bias (wih row from LDS)
        const int j = (tid - 128) % 96;
        biasC = bih[r * G3 + j];
    }

    // ---- one-time LDS weight staging ----
    for (int i = tid; i < 11 * L * M; i += BS) {      // wadd (v10 layout)
        const int e = i >> 9, rem = i & 511, l = rem >> 4, m = rem & 15;
        wadd_s[((e * 4 + (m >> 2)) * 32 + l) * 4 + (m & 3)] =
            add_w[((size_t)edgeE[e] * L + l) * M + m];
    }
    for (int i = tid; i < G3 * L; i += BS) {          // wih, XOR-swizzled
        const int j = i >> 5, cw = i & 31, c = cw >> 2, w = cw & 3;
        wih_s[j * 32 + ((c ^ (j & 7)) << 2) + w] = wih[(size_t)r * G3 * L + i];
    }

    // ---- state init ----
    for (int i = tid; i < G * R * L; i += BS) {
        const int g = i / (R * L), rl = i - g * (R * L);
        const int room = rl >> 5, l = rl & 31;
        zS[g * ZG + room * ZR + l] = z0[(size_t)(b0 + g) * R * L + rl];
    }
    for (int i = tid; i < G * HH; i += BS) {
        const int g = i >> 5, hh = i & 31;
        hSS[g * HS + hh] = h0[(size_t)(b0 + g) * R * HH + r * HH + hh];
    }
    __syncthreads();

    const float NANF = __uint_as_float(0xFFFFFFFFu);

    for (int t = 0; t < T; ++t) {
        // ---- P1: mean (0-351, x2 g) | gh (384-479, x4) | poison (480-511) ----
        if (tid < 352) {
            const int rowl = tid % 176;
            const int sr = edgeSrc[rowl >> 4];
            const int gb = (tid < 176) ? 0 : 2;
#pragma unroll
            for (int gg = 0; gg < 2; ++gg) {
                const int g = gb + gg;
                const float4* zp = (const float4*)(zS + g * ZG + sr * ZR);
                float a = biasA;
#pragma unroll
                for (int c = 0; c < 8; ++c) a = fma4(wbuf[c], zp[c], a);
                meanS[g * 176 + rowl] = a;
            }
        } else if (tid >= 384 && tid < 480) {
            const int j = tid - 384;
#pragma unroll
            for (int g = 0; g < G; ++g) {
                const float4* hp = (const float4*)(hSS + g * HS);
                float a = biasA;
#pragma unroll
                for (int c = 0; c < 8; ++c) a = fma4(wbuf[c], hp[c], a);
                ghSS[g * GG + j] = a;
            }
        } else if (tid >= 480 && t >= 1) {
            // Poison own record in buf (t-1)%3 (read 2 steps ago; causal proof
            // as v13/v14). Ack'd by W7's vmcnt(0) in P2.
            float* __restrict__ zq = zx + (size_t)((t - 1) % 3) * ZXN;
            const int i = tid - 480;              // 0..31
            const int g = i >> 3, l4 = i & 7;
            float* pp = zq + (size_t)(b0 + g) * (R * L) + r * L + l4 * 4;
#pragma unroll
            for (int w = 0; w < 4; ++w)
                __hip_atomic_store(pp + w, NANF, __ATOMIC_RELAXED,
                                   __HIP_MEMORY_SCOPE_AGENT);
        }
        sync_lds();

        // ---- P2: inc (0-127) | W7 drain ----
        if (tid < 128) {
            const int g = tid >> 5, l = tid & 31;
            const float4* mp = (const float4*)(meanS + g * 176);
            const float4* wp = (const float4*)wadd_s;
            float a = 0.f;
#pragma unroll
            for (int e = 0; e < 11; ++e)
#pragma unroll
                for (int c = 0; c < 4; ++c)
                    a = fma4(wp[(e * 4 + c) * 32 + l], mp[e * 4 + c], a);
            incS[g * IS + l] = a;
        } else if (tid >= 480) {
            // Wave 7: ack P1 poison stores before any later publish into that
            // buffer (next publish of it is step t+1 P4, many barriers later).
            asm volatile("s_waitcnt vmcnt(0)" ::: "memory");
        }
        sync_lds();

        // ---- P3: silu (0-255,x1) | gate (256-383,x1) | gi (128-511,x1) ----
        if (tid < 256) {
            const int j = tid & 63, g = tid >> 6;
            const float4* zp = (const float4*)(zS + g * ZG + r * ZR);
            const float4* ip = (const float4*)(incS + g * IS);
            float a = biasB;
#pragma unroll
            for (int c = 0; c < 8; ++c) {
                a = fma4(wbuf[8 + c], zp[c], a);
                a = fma4(wbuf[16 + c], ip[c], a);
            }
            shSS[g * SH + j] = a * sigmoidf(a);
        } else if (tid < 384) {
            const int k = tid - 256;
            const int j = k & 31, g = k >> 5;
            const float4* zp = (const float4*)(zS + g * ZG + r * ZR);
            const float4* ip = (const float4*)(incS + g * IS);
            float a = biasB;
#pragma unroll
            for (int c = 0; c < 8; ++c) {
                a = fma4(wbuf[8 + c], zp[c], a);
                a = fma4(wbuf[16 + c], ip[c], a);
            }
            gateS[g * GS + j] = sigmoidf(a);
        }
        if (tid >= 128) {                  // gi, swizzled wih_s
            const int k = tid - 128;                       // 0..383
            const int j = k % 96, g = k / 96;
            const float* wb = wih_s + j * 32;
            const int jx = j & 7;
            const float4* ip = (const float4*)(incS + g * IS);
            float a = biasC;
#pragma unroll
            for (int c = 0; c < 8; ++c)
                a = fma4(*(const float4*)(wb + ((c ^ jx) << 2)), ip[c], a);
            giSS[g * GG + j] = a;
        }
        sync_lds();

        // ---- P4: zout+publish (384-511; W6-7) | msgs->fetch (0-175)
        //         | GRU->fetch (176-303) | sleep->fetch (304-351) ----
        float* __restrict__ zxp = zx + (size_t)((t + 1) % 3) * ZXN;
        if (tid >= 384) {
            const int k = tid - 384;
            const int j = k & 31, g = k >> 5;
            const float4* sp = (const float4*)(shSS + g * SH);
            float a = biasB;
#pragma unroll
            for (int c = 0; c < 16; ++c) a = fma4(wbuf[8 + c], sp[c], a);
            const float target = tanhf(a);
            const float zv = zS[g * ZG + r * ZR + j];
            const float znew = zv + DT * gateS[g * GS + j] * (target - zv);
            zS[g * ZG + r * ZR + j] = znew;   // own-room z stays in LDS
            if (t + 1 < T)
                __hip_atomic_store(&zxp[(size_t)(b0 + g) * (R * L) + r * L + j],
                                   znew, __ATOMIC_RELAXED,
                                   __HIP_MEMORY_SCOPE_AGENT);
            __builtin_nontemporal_store(
                znew, &out_z[((size_t)(b0 + g) * T + t) * (R * L) + r * L + j]);
        } else {
            // pre-fetch cover for every fetch lane:
            if (tid < 176) {               // msgs (covers lanes 0-175)
                const int g = tid / 44, i = tid - g * 44;   // i in 0..43
                const int el = i >> 2, m4 = i & 3;
                const f4v v = *(const f4v*)(meanS + g * 176 + i * 4);
                __builtin_nontemporal_store(
                    v, (f4v*)&out_msgs[((size_t)(b0 + g) * T + t) * (E * M)
                                       + edgeE[el] * 16 + m4 * 4]);
            } else if (tid < 304) {        // GRU (covers lanes 176-303)
                const int i = tid - 176;
                const int g = i >> 5, hh = i & 31;
                const float ir  = giSS[g * GG + hh];
                const float iz  = giSS[g * GG + HH + hh];
                const float inn = giSS[g * GG + 2 * HH + hh];
                const float hr  = ghSS[g * GG + hh];
                const float hz  = ghSS[g * GG + HH + hh];
                const float hnv = ghSS[g * GG + 2 * HH + hh];
                const float reset = sigmoidf(ir + hr);
                const float upd   = sigmoidf(iz + hz);
                const float nw    = tanhf(inn + reset * hnv);
                hSS[g * HS + hh] = (1.0f - upd) * nw + upd * hSS[g * HS + hh];
            } else if (tid < 352) {        // cover lanes 304-351 with a nap
                if (t + 1 < T) __builtin_amdgcn_s_sleep(4);
            }
            if (tid < 352 && t + 1 < T) {  // fetch: chunk c = tid (0..351)
                const int team = tid >> 5, rem = tid & 31;
                const int s    = team + (team >= r ? 1 : 0);   // remote room
                const int g    = rem >> 3, l4 = rem & 7;
                const float* sp =
                    zxp + (size_t)(b0 + g) * (R * L) + s * L + l4 * 4;
                float4 v;
                for (;;) {
                    v.x = __hip_atomic_load(sp + 0, __ATOMIC_RELAXED, __HIP_MEMORY_SCOPE_AGENT);
                    v.y = __hip_atomic_load(sp + 1, __ATOMIC_RELAXED, __HIP_MEMORY_SCOPE_AGENT);
                    v.z = __hip_atomic_load(sp + 2, __ATOMIC_RELAXED, __HIP_MEMORY_SCOPE_AGENT);
                    v.w = __hip_atomic_load(sp + 3, __ATOMIC_RELAXED, __HIP_MEMORY_SCOPE_AGENT);
                    if (v.x == v.x && v.y == v.y && v.z == v.z && v.w == v.w)
                        break;
                    __builtin_amdgcn_s_sleep(1);
                }
                *(float4*)(zS + g * ZG + s * ZR + l4 * 4) = v;
            }
        }
        sync_lds();
    }

    // ---- final h ----
    for (int i = tid; i < G * HH; i += BS) {
        const int g = i >> 5, hh = i & 31;
        __builtin_nontemporal_store(
            hSS[g * HS + hh], &out_hf[(size_t)(b0 + g) * R * HH + r * HH + hh]);
    }
}

extern "C" void kernel_launch(void* const* d_in, const int* in_sizes, int n_in,
                              void* d_out, int out_size, void* d_ws, size_t ws_size,
                              hipStream_t stream) {
    const float* z0     = (const float*)d_in[0];
    const float* h0     = (const float*)d_in[1];
    const float* mean_w = (const float*)d_in[2];
    const float* mean_b = (const float*)d_in[3];
    const float* add_w  = (const float*)d_in[4];
    const float* gsw    = (const float*)d_in[5];
    const float* gsb    = (const float*)d_in[6];
    const float* gcw    = (const float*)d_in[7];
    const float* lw     = (const float*)d_in[8];
    const float* lb     = (const float*)d_in[9];
    const float* ow_w   = (const float*)d_in[10];
    const float* ob     = (const float*)d_in[11];
    const float* wih    = (const float*)d_in[12];
    const float* whh    = (const float*)d_in[13];
    const float* bih    = (const float*)d_in[14];
    const float* bhh    = (const float*)d_in[15];
    const int* src_idx  = (const int*)d_in[16];
    const int* tgt_idx  = (const int*)d_in[17];
    const int* n_steps  = (const int*)d_in[18];

    const int B  = in_sizes[0] / (R * L);
    const int NG = B / G;   // batch groups

    float* zx = (float*)d_ws;    // 3 rotating buffers of B*R*L floats

    // Pre-poison all three buffers: every word = 0xFFFFFFFF = NaN sentinel.
    (void)hipMemsetAsync(zx, 0xFF, (size_t)3 * B * R * L * sizeof(float), stream);

    // 72000 B dynamic LDS (+~51KB static = ~123KB) => at most one block per CU
    // => no persistent CU-sharing stragglers.
    nv_main<<<dim3(R, NG), dim3(BS), 72000, stream>>>(
        z0, h0, mean_w, mean_b, add_w, gsw, gsb, gcw, lw, lb, ow_w, ob,
        wih, whh, bih, bhh, src_idx, tgt_idx, n_steps,
        zx, (float*)d_out, B);
}